// Round 11
// baseline (318.300 us; speedup 1.0000x reference)
//
#include <hip/hip_runtime.h>
#include <stdint.h>

// Problem constants
#define B_SZ   32
#define NIN    2312
#define NHID   512
#define NOUT   10
#define T_SZ   350
#define NW32   73                 // ceil(2312/32) bitmask words per input column
#define NW64   8                  // 512/64 ballot words per hidden column
#define NHALF  256                // output half-width for L2-resident W1
#define NROW   2313               // NIN + 1 dummy zero row (branch-free padding)

// psp (SRM) kernel eps[n] = CS * n * DS^n, DS = exp(-0.1), CS = e/10
#define DS_D   0.9048374180359595
#define CS_D   0.2718281828459045
#define D100_D 4.5399929762484854e-05   // exp(-10) = DS^100
// refractory recurrence in fp32, exactly like the reference scan
#define DREF_F 0.36787944117144233f     // exp(-1)
#define CREF_F -54.36563656918091f      // -2*10*e

// scan chunking (k45/k6): 7 chunks of 50; psp-IIR warm-started <=100 steps
// early is EXACT (FIR truncated at 100 taps); refractory burn-in error decays
// e^-n -> < 1e-28 by chunk start (absorbed below fp32 ulp).
#define NCHUNK 7
#define CLEN   50
#define NPF    10                 // ring depth; 50/100/150 all %10==0

// ---------------------------------------------------------------------------
// K12: fused bitpack (blocks 0..2335) + W1 half-split pack (2336..3503) +
//      dummy-zero-row fill (block 3504). Bitpack float4 streaming.
__global__ __launch_bounds__(384) void k12(const float* __restrict__ x,
                                           const float* __restrict__ W1,
                                           uint32_t* __restrict__ bits1,
                                           float* __restrict__ W1s) {
    __shared__ float lds[32 * T_SZ];   // 44.8 KB
    const int bid = blockIdx.x;
    const int tid = threadIdx.x;
    if (bid < NW32 * B_SZ) {
        // --- bitpack: block = (b, w); contiguous rowsx350 tile -> LDS -> pack
        const int w = bid % NW32;
        const int b = bid / NW32;
        const int rows = (NIN - (w << 5) < 32) ? (NIN - (w << 5)) : 32;  // 32 or 8
        const float* base = x + ((size_t)(b * NIN + (w << 5))) * T_SZ;
        const int nf4 = (rows * T_SZ) >> 2;     // rows even -> divisible by 4
        for (int f = tid; f < nf4; f += 384)
            ((float4*)lds)[f] = ((const float4*)base)[f];
        __syncthreads();
        if (tid < T_SZ) {
            uint32_t bits = 0;
            for (int j = 0; j < rows; ++j)
                bits |= (lds[j * T_SZ + tid] > 0.5f) ? (1u << j) : 0u;
            bits1[(size_t)(b * T_SZ + tid) * NW32 + w] = bits;
        }
    } else if (bid < NW32 * B_SZ + NW32 * 16) {
        // --- pack W1 [512, 2312] -> W1s[h][i][256], h = o>>8
        float (*tile)[33] = (float (*)[33])lds;
        const int bb = bid - NW32 * B_SZ;
        const int i0 = (bb % NW32) * 32, o0 = (bb / NW32) * 32;
        const int tx = tid & 31, ty = tid >> 5;  // ty 0..11
#pragma unroll
        for (int r = 0; r < 3; ++r) {
            int row = ty + 12 * r;
            if (row < 32) {
                int o = o0 + row, i = i0 + tx;
                if (i < NIN) tile[row][tx] = W1[(size_t)o * NIN + i];
            }
        }
        __syncthreads();
#pragma unroll
        for (int r = 0; r < 3; ++r) {
            int row = ty + 12 * r;
            if (row < 32) {
                int i = i0 + row, o = o0 + tx;
                if (i < NIN)
                    W1s[((size_t)(o >> 8) * NROW + i) * NHALF + (o & 255)] = tile[tx][row];
            }
        }
    } else {
        // --- dummy zero row i = NIN for both halves
        if (tid < NHALF) {
            W1s[((size_t)0 * NROW + NIN) * NHALF + tid] = 0.0f;
            W1s[((size_t)1 * NROW + NIN) * NHALF + tid] = 0.0f;
        }
    }
}

// ---------------------------------------------------------------------------
// K3: sparse dense1 gather, TWO columns per block. Amortizes the prefix-scan
// and compaction setup over 2 columns (waves 0/1 scan col A/B in parallel)
// and interleaves two independent row streams -> 8 b128 loads in flight, 2
// acc chains. Per-column row traversal order identical to the 1-col version
// (r, r+4, r+8, r+12 stepping 16) -> bit-identical sums.
__global__ __launch_bounds__(256) void k3_dense1(const uint32_t* __restrict__ bits1,
                                                 const float* __restrict__ W1s,
                                                 float* __restrict__ z1ct) {
    __shared__ uint32_t words[2][128];
    __shared__ uint16_t pfx[2][80];
    __shared__ uint16_t idxbuf[2][NIN + 16];
    __shared__ float red[2][3][NHALF];
    __shared__ float fin[2][NHALF];

    const int btA = blockIdx.x * 2;     // 11200 columns over 5600 blocks
    const int btB = btA + 1;
    const int h = blockIdx.y;           // 0 or 1
    const int tid = threadIdx.x;
    const int wv = tid >> 6, lane = tid & 63;

    if (tid < 128) {
        words[0][tid] = (tid < NW32) ? bits1[(size_t)btA * NW32 + tid] : 0u;
        words[1][tid] = (tid < NW32) ? bits1[(size_t)btB * NW32 + tid] : 0u;
    }
    __syncthreads();

    // parallel shfl prefix scans: wave 0 -> col A, wave 1 -> col B
    if (wv < 2) {
        uint32_t w0 = words[wv][lane];
        uint32_t w1 = words[wv][lane + 64];
        int p0 = __popc(w0), p1 = __popc(w1);
        int s0 = p0, s1 = p1;
#pragma unroll
        for (int off = 1; off < 64; off <<= 1) {
            int u0 = __shfl_up(s0, off);
            int u1 = __shfl_up(s1, off);
            if (lane >= off) { s0 += u0; s1 += u1; }
        }
        int tot0 = __shfl(s0, 63);
        pfx[wv][lane] = (uint16_t)(s0 - p0);
        if (lane < 9) pfx[wv][lane + 64] = (uint16_t)(tot0 + s1 - p1);
        if (lane == 8) pfx[wv][73] = (uint16_t)(tot0 + s1);   // ntot
    }
    __syncthreads();

    const int ntotA = pfx[0][73], ntotB = pfx[1][73];
    const int npadA = (ntotA + 15) & ~15;
    const int npadB = (ntotB + 15) & ~15;
    // compaction: threads 0..72 -> col A, threads 128..200 -> col B
    if (tid < NW32) {
        uint32_t m = words[0][tid];
        int p = pfx[0][tid];
        while (m) {
            int j = __builtin_ctz(m);
            m &= m - 1;
            idxbuf[0][p++] = (uint16_t)((tid << 5) + j);
        }
    } else if (tid >= 128 && tid < 128 + NW32) {
        const int tw = tid - 128;
        uint32_t m = words[1][tw];
        int p = pfx[1][tw];
        while (m) {
            int j = __builtin_ctz(m);
            m &= m - 1;
            idxbuf[1][p++] = (uint16_t)((tw << 5) + j);
        }
    }
    if (tid >= 240) {                   // pad col A to x16 with zero row
        int k = tid - 240;
        if (ntotA + k < npadA) idxbuf[0][ntotA + k] = (uint16_t)NIN;
    }
    if (tid >= 224 && tid < 240) {      // pad col B
        int k = tid - 224;
        if (ntotB + k < npadB) idxbuf[1][ntotB + k] = (uint16_t)NIN;
    }
    __syncthreads();

    const float* Wh = W1s + (size_t)h * NROW * NHALF;
    float4 accA = make_float4(0.f, 0.f, 0.f, 0.f);
    float4 accB = make_float4(0.f, 0.f, 0.f, 0.f);
    const int npadMax = (npadA > npadB) ? npadA : npadB;
    for (int r = wv; r < npadMax; r += 16) {
        if (r < npadA) {                // wave-uniform branch
            int i0 = idxbuf[0][r], i1 = idxbuf[0][r + 4];
            int i2 = idxbuf[0][r + 8], i3 = idxbuf[0][r + 12];
            float4 v0 = ((const float4*)(Wh + (size_t)i0 * NHALF))[lane];
            float4 v1 = ((const float4*)(Wh + (size_t)i1 * NHALF))[lane];
            float4 v2 = ((const float4*)(Wh + (size_t)i2 * NHALF))[lane];
            float4 v3 = ((const float4*)(Wh + (size_t)i3 * NHALF))[lane];
            accA.x += v0.x; accA.y += v0.y; accA.z += v0.z; accA.w += v0.w;
            accA.x += v1.x; accA.y += v1.y; accA.z += v1.z; accA.w += v1.w;
            accA.x += v2.x; accA.y += v2.y; accA.z += v2.z; accA.w += v2.w;
            accA.x += v3.x; accA.y += v3.y; accA.z += v3.z; accA.w += v3.w;
        }
        if (r < npadB) {
            int j0 = idxbuf[1][r], j1 = idxbuf[1][r + 4];
            int j2 = idxbuf[1][r + 8], j3 = idxbuf[1][r + 12];
            float4 u0 = ((const float4*)(Wh + (size_t)j0 * NHALF))[lane];
            float4 u1 = ((const float4*)(Wh + (size_t)j1 * NHALF))[lane];
            float4 u2 = ((const float4*)(Wh + (size_t)j2 * NHALF))[lane];
            float4 u3 = ((const float4*)(Wh + (size_t)j3 * NHALF))[lane];
            accB.x += u0.x; accB.y += u0.y; accB.z += u0.z; accB.w += u0.w;
            accB.x += u1.x; accB.y += u1.y; accB.z += u1.z; accB.w += u1.w;
            accB.x += u2.x; accB.y += u2.y; accB.z += u2.z; accB.w += u2.w;
            accB.x += u3.x; accB.y += u3.y; accB.z += u3.z; accB.w += u3.w;
        }
    }
    if (wv > 0) {
        ((float4*)red[0][wv - 1])[lane] = accA;
        ((float4*)red[1][wv - 1])[lane] = accB;
    }
    __syncthreads();
    if (wv == 0) {
        float4 a1 = ((float4*)red[0][0])[lane];
        float4 a2 = ((float4*)red[0][1])[lane];
        float4 a3 = ((float4*)red[0][2])[lane];
        accA.x = ((accA.x + a1.x) + a2.x) + a3.x;
        accA.y = ((accA.y + a1.y) + a2.y) + a3.y;
        accA.z = ((accA.z + a1.z) + a2.z) + a3.z;
        accA.w = ((accA.w + a1.w) + a2.w) + a3.w;
        ((float4*)fin[0])[lane] = accA;
        float4 b1 = ((float4*)red[1][0])[lane];
        float4 b2 = ((float4*)red[1][1])[lane];
        float4 b3 = ((float4*)red[1][2])[lane];
        accB.x = ((accB.x + b1.x) + b2.x) + b3.x;
        accB.y = ((accB.y + b1.y) + b2.y) + b3.y;
        accB.z = ((accB.z + b1.z) + b2.z) + b3.z;
        accB.w = ((accB.w + b1.w) + b2.w) + b3.w;
        ((float4*)fin[1])[lane] = accB;
    }
    __syncthreads();
    const int och = (h << 8) + tid;
    const int oc = och >> 6, l6 = och & 63;
    {
        int b = btA / T_SZ, t = btA - b * T_SZ;
        z1ct[((size_t)(b * NW64 + oc) * T_SZ + t) * 64 + l6] = fin[0][tid];
        b = btB / T_SZ; t = btB - b * T_SZ;
        z1ct[((size_t)(b * NW64 + oc) * T_SZ + t) * 64 + l6] = fin[1][tid];
    }
}

// ---------------------------------------------------------------------------
// K45: fused layer-1 scan + dense2. Block = (b, chunk), 512 threads = 8 waves;
// wave wv scans channels wv*64..+63 (chunked IIR, exact), ballots into LDS;
// then 500 (t,o) pairs compute z2 in the same wv/ctz-ascending order.
__global__ __launch_bounds__(512) void k45(const float* __restrict__ z1ct,
                                           const float* __restrict__ W2,
                                           float* __restrict__ z2ct) {
    __shared__ float W2s[NHID * NOUT];      // [c][o], 20 KB
    __shared__ uint64_t sw[CLEN][NW64];     // s1 ballot words for my 50 t's
    const int tid = threadIdx.x;
    const int wv = tid >> 6, lane = tid & 63;
    const int b = blockIdx.x / NCHUNK;
    const int ck = blockIdx.x % NCHUNK;
    const int tstart = ck * CLEN;
    const int tend = tstart + CLEN;
    const int t0 = (tstart >= 100) ? tstart - 100 : 0;

    for (int k = tid; k < NHID * NOUT; k += 512) {
        int c = k / NOUT, o = k - c * NOUT;
        W2s[k] = W2[(size_t)o * NHID + c];
    }

    // ---- layer-1 chunked scan (identical math to old k4)
    const float* base = z1ct + (size_t)(b * NW64 + wv) * T_SZ * 64 + lane;
    double A = 0.0, Bs = 0.0, A2 = 0.0, Bs2 = 0.0;
    float ra = 0.0f, rb = 0.0f;
    const double TAIL = D100_D * CS_D;
    float xb[NPF], xdb[NPF];
#pragma unroll
    for (int i = 0; i < NPF; ++i) {
        int t = t0 + i;
        xb[i] = base[(size_t)t * 64];
        int td = t - 100;
        xdb[i] = (td >= 0) ? base[(size_t)td * 64] : 0.0f;
    }
    for (int tb = t0; tb < tend; tb += NPF) {
#pragma unroll
        for (int i = 0; i < NPF; ++i) {
            const int t = tb + i;
            float x = xb[i], xd = xdb[i];
            const int tn = t + NPF;
            xb[i] = (tn < T_SZ) ? base[(size_t)tn * 64] : 0.0f;
            const int td = tn - 100;
            xdb[i] = (td >= 0) ? base[(size_t)td * 64] : 0.0f;
            Bs = DS_D * Bs + DS_D * A;
            A = DS_D * A + (double)x;
            Bs2 = DS_D * Bs2 + DS_D * A2;
            A2 = DS_D * A2 + (double)xd;
            double y = CS_D * Bs - TAIL * (Bs2 + 100.0 * A2);
            float u = (float)y + CREF_F * rb;
            float s = (u >= 10.0f) ? 1.0f : 0.0f;
            float ran = DREF_F * ra + s;
            float rbn = DREF_F * rb + DREF_F * ra;
            ra = ran; rb = rbn;
            uint64_t mball = __ballot(s != 0.0f);
            if (t >= tstart && lane == 0) sw[t - tstart][wv] = mball;
        }
    }
    __syncthreads();

    // ---- dense2 for my 50 t's (same order as old k5 -> bit-identical)
    if (tid < CLEN * NOUT) {                // 500 of 512
        const int tr = tid / NOUT;
        const int o = tid - tr * NOUT;
        const int t = tstart + tr;
        float acc = 0.f;
#pragma unroll
        for (int w2 = 0; w2 < NW64; ++w2) {
            uint64_t m = sw[tr][w2];
            while (m) {
                int j = __builtin_ctzll(m);
                m &= m - 1;
                acc += W2s[((w2 << 6) + j) * NOUT + o];
            }
        }
        const int bo = b * NOUT + o;
        z2ct[((size_t)(bo >> 6) * T_SZ + t) * 64 + (bo & 63)] = acc;
    }
}

// ---------------------------------------------------------------------------
// K6: fused psp-IIR + refractory scan, layer 2, chunked. Writes [B, NOUT, T].
__global__ __launch_bounds__(64) void k6_fir_scan2(const float* __restrict__ z2ct,
                                                   float* __restrict__ out) {
    const int lane = threadIdx.x;
    const int g = blockIdx.x / NCHUNK;    // bo group 0..4
    const int ck = blockIdx.x % NCHUNK;
    const int tstart = ck * CLEN;
    const int tend = tstart + CLEN;
    const int t0 = (tstart >= 100) ? tstart - 100 : 0;
    const int bo = (g << 6) + lane;       // 0..319
    const float* base = z2ct + (size_t)g * T_SZ * 64 + lane;
    float* op = out + (size_t)bo * T_SZ;
    double A = 0.0, Bs = 0.0, A2 = 0.0, Bs2 = 0.0;
    float ra = 0.0f, rb = 0.0f;
    const double TAIL = D100_D * CS_D;
    float xb[NPF], xdb[NPF];
#pragma unroll
    for (int i = 0; i < NPF; ++i) {
        int t = t0 + i;
        xb[i] = base[(size_t)t * 64];
        int td = t - 100;
        xdb[i] = (td >= 0) ? base[(size_t)td * 64] : 0.0f;
    }
    for (int tb = t0; tb < tend; tb += NPF) {
#pragma unroll
        for (int i = 0; i < NPF; ++i) {
            const int t = tb + i;
            float x = xb[i], xd = xdb[i];
            const int tn = t + NPF;
            xb[i] = (tn < T_SZ) ? base[(size_t)tn * 64] : 0.0f;
            const int td = tn - 100;
            xdb[i] = (td >= 0) ? base[(size_t)td * 64] : 0.0f;
            Bs = DS_D * Bs + DS_D * A;
            A = DS_D * A + (double)x;
            Bs2 = DS_D * Bs2 + DS_D * A2;
            A2 = DS_D * A2 + (double)xd;
            double y = CS_D * Bs - TAIL * (Bs2 + 100.0 * A2);
            float u = (float)y + CREF_F * rb;
            float s = (u >= 10.0f) ? 1.0f : 0.0f;
            float ran = DREF_F * ra + s;
            float rbn = DREF_F * rb + DREF_F * ra;
            ra = ran; rb = rbn;
            if (t >= tstart) op[t] = s;
        }
    }
}

// ---------------------------------------------------------------------------
extern "C" void kernel_launch(void* const* d_in, const int* in_sizes, int n_in,
                              void* d_out, int out_size, void* d_ws, size_t ws_size,
                              hipStream_t stream) {
    const float* spikeInput = (const float*)d_in[0];  // [32, 2312, 350]
    const float* W1 = (const float*)d_in[1];          // [512, 2312]
    const float* W2 = (const float*)d_in[2];          // [10, 512]
    float* out = (float*)d_out;                       // [32, 10, 350]

    char* ws = (char*)d_ws;
    float* W1s = (float*)(ws + 0);                        //  4,737,024 B (2313 rows x 2 halves)
    uint32_t* bits1 = (uint32_t*)(ws + 4737024);          //  3,270,400 B
    float* z1ct = (float*)(ws + 8007424);                 // 22,937,600 B
    // z2ct aliases bits1's region: bits1 is dead after k3, z2ct written by k45.
    float* z2ct = (float*)(ws + 4737024);                 //    448,000 B (alias)
    // total: 30,945,024 B

    k12<<<NW32 * B_SZ + NW32 * 16 + 1, 384, 0, stream>>>(spikeInput, W1, bits1, W1s);
    k3_dense1<<<dim3(B_SZ * T_SZ / 2, 2), 256, 0, stream>>>(bits1, W1s, z1ct);
    k45<<<B_SZ * NCHUNK, 512, 0, stream>>>(z1ct, W2, z2ct);
    k6_fir_scan2<<<5 * NCHUNK, 64, 0, stream>>>(z2ct, out);
}